// Round 17
// baseline (473.753 us; speedup 1.0000x reference)
//
#include <hip/hip_runtime.h>
#include <hip/hip_bf16.h>
#include <cstdint>

// Problem constants
#define B_ROWS 16384
#define DIN    8192
#define NE_    4      // codebook entries
#define NEXP   8
#define HDEC   256
#define NCOL   40     // 8 gate cols + 32 (e,lat) cols
#define CHUNK  256    // K per staged chunk (4 floats/lane)
#define NCHUNK (DIN / CHUNK)   // 32
#define RPB    8      // rows per block
#define CPW    5      // cols per wave
#define PREP_BLOCKS ((NCOL * DIN) / 256)   // 1280

typedef float f32x4 __attribute__((ext_vector_type(4)));

// ---------------- helpers ----------------
__device__ __forceinline__ float mishf(float x) {
    float sp = (x > 20.f) ? x : log1pf(expf(x));
    return x * tanhf(sp);
}
__device__ __forceinline__ double mishd(double x) {
    double sp = (x > 30.0) ? x : log1p(exp(x));
    return x * tanh(sp);
}
__device__ __forceinline__ void ln4d(const double* a, double* o) {
    double m  = (a[0] + a[1] + a[2] + a[3]) * 0.25;
    double d0 = a[0] - m, d1 = a[1] - m, d2 = a[2] - m, d3 = a[3] - m;
    double v  = (d0*d0 + d1*d1 + d2*d2 + d3*d3) * 0.25;
    double r  = 1.0 / sqrt(v + 1e-5);
    o[0] = d0*r; o[1] = d1*r; o[2] = d2*r; o[3] = d3*r;
}

// ---------------------------------------------------------------------------
__global__ __launch_bounds__(256) void sentinel_k(float* __restrict__ out, int n, float v) {
    int i = blockIdx.x * 256 + threadIdx.x;
    if (i < n) out[i] = v;
}

// ---------------------------------------------------------------------------
// Kernel 1 (merged): blocks [0,1280) pack w40T; blocks [1280,1312) compute
// decoder expert outputs outE[c][e][8] (one block per (c,e)). Both 256 thr.
// ---------------------------------------------------------------------------
__device__ __forceinline__ float blk_sum256(float v, volatile float* red) {
    #pragma unroll
    for (int off = 32; off > 0; off >>= 1) v += __shfl_down(v, off, 64);
    int lane = threadIdx.x & 63, w = threadIdx.x >> 6;
    if (lane == 0) red[w] = v;
    __syncthreads();
    float s = red[0] + red[1] + red[2] + red[3];
    __syncthreads();
    return s;
}

__global__ __launch_bounds__(256) void prep_all(
    const float* __restrict__ gw,  const float* __restrict__ ew1,
    float* __restrict__ w40t,
    const float* __restrict__ w1,  const float* __restrict__ b1,
    const float* __restrict__ w2,  const float* __restrict__ b2,
    const float* __restrict__ w3,  const float* __restrict__ b3,
    const float* __restrict__ w4,  const float* __restrict__ b4,
    float* __restrict__ outE)
{
    __shared__ float h[HDEC];
    __shared__ float red[4];

    if (blockIdx.x < PREP_BLOCKS) {
        int idx = blockIdx.x * 256 + threadIdx.x;   // 40*8192 threads
        int j = idx >> 13, k = idx & (DIN - 1);
        float v;
        if (j < 8) {
            v = gw[k * 8 + j];
        } else {
            int e = (j - 8) >> 2, hh = (j - 8) & 3;
            v = ew1[((size_t)e * DIN + k) * 4 + hh];
        }
        w40t[idx] = v;   // coalesced write
        return;
    }

    int bid = blockIdx.x - PREP_BLOCKS;
    int c = bid >> 3, e = bid & 7, t = threadIdx.x;

    float a   = mishf(w1[((size_t)e * NE_ + c) * HDEC + t] + b1[e * HDEC + t]);
    float m   = blk_sum256(a, red) * (1.f / HDEC);
    float d   = a - m;
    float var = blk_sum256(d * d, red) * (1.f / HDEC);
    h[t] = d * rsqrtf(var + 1e-5f);
    __syncthreads();

    float s = b2[e * HDEC + t];
    #pragma unroll 16
    for (int i = 0; i < HDEC; ++i) s += h[i] * w2[((size_t)e * HDEC + i) * HDEC + t];
    __syncthreads();
    a   = mishf(s);
    m   = blk_sum256(a, red) * (1.f / HDEC);
    d   = a - m;
    var = blk_sum256(d * d, red) * (1.f / HDEC);
    h[t] = d * rsqrtf(var + 1e-5f);
    __syncthreads();

    s = b3[e * HDEC + t];
    #pragma unroll 16
    for (int i = 0; i < HDEC; ++i) s += h[i] * w3[((size_t)e * HDEC + i) * HDEC + t];
    __syncthreads();
    float h3 = mishf(s);

    for (int j = 0; j < 8; ++j) {
        float oj = blk_sum256(h3 * w4[((size_t)e * HDEC + t) * 8 + j], red);
        if (t == 0) outE[((size_t)c * 8 + e) * 8 + j] = oj + b4[e * 8 + j];
    }
}

// ---------------------------------------------------------------------------
// Kernel 2: skinny GEMM with a barrier-surviving pipeline (8-phase idiom):
// 3-buffer LDS ring, stage depth 2, raw s_barrier + counted vmcnt (never a
// full drain in the loop). Per chunk c (steady):
//   enter with [st(c+1)x2] outstanding
//   issue w(c)x5 ; issue st(c+2)x2 ; vmcnt(2) retires st(c+1)+w(c),
//   leaves st(c+2) in flight ; FMA on buf[c%3] ; s_barrier (no wait).
// Block/wave mapping, registers, FMA order bit-identical to R15/R16
// (verified numerics). 4096 blocks x 256 thr; LDS 24 KB -> 6 blocks/CU.
// ---------------------------------------------------------------------------
#define SB __builtin_amdgcn_sched_barrier(0)
#define WAITVM_(n) asm volatile("s_waitcnt vmcnt(" #n ")")
#define WAITVM(n)  WAITVM_(n)

#define STAGE2(cc, BUF)                                                       \
    {                                                                         \
        __builtin_amdgcn_global_load_lds(                                     \
            (gp_t)(const void*)(xsrcA + (size_t)(cc) * CHUNK),                \
            (lp_t)(void*)(&xbuf[BUF][wv][lane << 2]), 16, 0, 0);              \
        __builtin_amdgcn_global_load_lds(                                     \
            (gp_t)(const void*)(xsrcB + (size_t)(cc) * CHUNK),                \
            (lp_t)(void*)(&xbuf[BUF][wv + 4][lane << 2]), 16, 0, 0);          \
    }

#define BODY(cc, BR, BS, VN, DOST, DOBAR)                                     \
    {                                                                         \
        f32x4 wv0 = *(const f32x4*)(wr + (size_t)(cc) * CHUNK);               \
        f32x4 wv1 = *(const f32x4*)(wr + (size_t)DIN     + (size_t)(cc) * CHUNK); \
        f32x4 wv2 = *(const f32x4*)(wr + 2 * (size_t)DIN + (size_t)(cc) * CHUNK); \
        f32x4 wv3 = *(const f32x4*)(wr + 3 * (size_t)DIN + (size_t)(cc) * CHUNK); \
        f32x4 wv4 = *(const f32x4*)(wr + 4 * (size_t)DIN + (size_t)(cc) * CHUNK); \
        SB;                                                                   \
        if (DOST) STAGE2((cc) + 2, BS);                                       \
        SB;                                                                   \
        WAITVM(VN);                                                           \
        SB;                                                                   \
        _Pragma("unroll")                                                     \
        for (int r = 0; r < RPB; ++r) {                                       \
            f32x4 xv = *(const f32x4*)(&xbuf[BR][r][lane << 2]);              \
            float a0 = acc[r][0];                                             \
            a0 = fmaf(xv.x, wv0.x, a0); a0 = fmaf(xv.y, wv0.y, a0);           \
            a0 = fmaf(xv.z, wv0.z, a0); a0 = fmaf(xv.w, wv0.w, a0);           \
            acc[r][0] = a0;                                                   \
            float a1 = acc[r][1];                                             \
            a1 = fmaf(xv.x, wv1.x, a1); a1 = fmaf(xv.y, wv1.y, a1);           \
            a1 = fmaf(xv.z, wv1.z, a1); a1 = fmaf(xv.w, wv1.w, a1);           \
            acc[r][1] = a1;                                                   \
            float a2 = acc[r][2];                                             \
            a2 = fmaf(xv.x, wv2.x, a2); a2 = fmaf(xv.y, wv2.y, a2);           \
            a2 = fmaf(xv.z, wv2.z, a2); a2 = fmaf(xv.w, wv2.w, a2);           \
            acc[r][2] = a2;                                                   \
            float a3 = acc[r][3];                                             \
            a3 = fmaf(xv.x, wv3.x, a3); a3 = fmaf(xv.y, wv3.y, a3);           \
            a3 = fmaf(xv.z, wv3.z, a3); a3 = fmaf(xv.w, wv3.w, a3);           \
            acc[r][3] = a3;                                                   \
            float a4 = acc[r][4];                                             \
            a4 = fmaf(xv.x, wv4.x, a4); a4 = fmaf(xv.y, wv4.y, a4);           \
            a4 = fmaf(xv.z, wv4.z, a4); a4 = fmaf(xv.w, wv4.w, a4);           \
            acc[r][4] = a4;                                                   \
        }                                                                     \
        SB;                                                                   \
        if (DOBAR) { __builtin_amdgcn_s_barrier(); SB; }                      \
    }

__global__ __launch_bounds__(256) void gemm_main(
    const float* __restrict__ x, const float* __restrict__ w40t,
    double* __restrict__ y)
{
    __shared__ float xbuf[3][RPB][CHUNK];   // 24576 B (3-deep ring)

    const int t    = threadIdx.x;
    const int lane = t & 63;
    const int wv   = t >> 6;            // 0..3
    const int bid  = blockIdx.x;
    const int rowGroup = (bid >> 4) * 8 + (bid & 7);   // bijective
    const int colHalf  = (bid >> 3) & 1;               // twin differs by 8
    const int rowBase  = rowGroup * RPB;
    const int j0   = colHalf * 20 + wv * CPW;

    typedef const char __attribute__((address_space(1)))* gp_t;
    typedef char __attribute__((address_space(3)))* lp_t;

    const float* __restrict__ xsrcA = x + (size_t)(rowBase + wv)     * DIN + (lane << 2);
    const float* __restrict__ xsrcB = x + (size_t)(rowBase + wv + 4) * DIN + (lane << 2);
    const float* __restrict__ wr    = w40t + (size_t)j0 * DIN + (lane << 2);

    float acc[RPB][CPW];
    #pragma unroll
    for (int r = 0; r < RPB; ++r)
        #pragma unroll
        for (int jj = 0; jj < CPW; ++jj) acc[r][jj] = 0.f;

    // ---- prologue: st(0)->buf0, st(1)->buf1; retire st(0), keep st(1)
    STAGE2(0, 0);
    STAGE2(1, 1);
    SB;
    WAITVM(2);          // retires st(0)x2; st(1)x2 in flight
    SB;
    __builtin_amdgcn_s_barrier();
    SB;

    // ---- chunks 0..29 in groups of 3 (bufR = c%3, bufS = (c+2)%3)
    for (int c3 = 0; c3 < 30; c3 += 3) {
        BODY(c3 + 0, 0, 2, 2, 1, 1);
        BODY(c3 + 1, 1, 0, 2, 1, 1);
        BODY(c3 + 2, 2, 1, 2, 1, 1);
    }
    // chunk 30: enter [st31x2]; +w30x5; no stage; vmcnt(0) retires all
    BODY(30, 0, 0, 0, 0, 1);
    // chunk 31: queue empty; +w31x5; vmcnt(0); no barrier
    BODY(31, 1, 0, 0, 0, 0);

    // ---- f64 cross-lane reduction (identical to R6/R12, verified)
    #pragma unroll
    for (int r = 0; r < RPB; ++r) {
        #pragma unroll
        for (int jj = 0; jj < CPW; ++jj) {
            double v = (double)acc[r][jj];
            #pragma unroll
            for (int off = 32; off > 0; off >>= 1) v += __shfl_xor(v, off, 64);
            if (lane == 0) y[(size_t)(rowBase + r) * NCOL + (j0 + jj)] = v;
        }
    }
}

// ---------------------------------------------------------------------------
// Kernel 3: per-row f64 tail (verified math). 1 thread = 1 row.
// 256 blocks x 64 threads -> all CUs.
// ---------------------------------------------------------------------------
__global__ __launch_bounds__(64) void tail_k(
    const double* __restrict__ yg, const float* __restrict__ outE,
    const float* __restrict__ gu,  const float* __restrict__ cb,
    const float* __restrict__ egb, const float* __restrict__ eb1,
    const float* __restrict__ ew2, const float* __restrict__ eb2,
    const float* __restrict__ ew3, const float* __restrict__ eb3,
    const float* __restrict__ ew4, const float* __restrict__ eb4,
    const float* __restrict__ dgw, const float* __restrict__ dgb,
    float* __restrict__ out)
{
    const int row = blockIdx.x * 64 + threadIdx.x;
    const double* __restrict__ y = yg + (size_t)row * NCOL;

    // encoder gate softmax
    double gv[8], mx = -1e300, gs = 0.0;
    #pragma unroll
    for (int e = 0; e < 8; ++e) { gv[e] = y[e] + (double)egb[e]; mx = fmax(mx, gv[e]); }
    #pragma unroll
    for (int e = 0; e < 8; ++e) { gv[e] = exp(gv[e] - mx); gs += gv[e]; }
    double inv = 1.0 / gs;

    double est[4] = {0, 0, 0, 0};
    #pragma unroll
    for (int e = 0; e < 8; ++e) {
        double a[4], l1[4], p2[4], l2[4], h3[4];
        #pragma unroll
        for (int hh = 0; hh < 4; ++hh)
            a[hh] = mishd(y[8 + e * 4 + hh] + (double)eb1[e * 4 + hh]);
        ln4d(a, l1);
        #pragma unroll
        for (int hh = 0; hh < 4; ++hh) {
            double s = (double)eb2[e * 4 + hh];
            #pragma unroll
            for (int i = 0; i < 4; ++i) s += l1[i] * (double)ew2[(e * 4 + i) * 4 + hh];
            p2[hh] = mishd(s);
        }
        ln4d(p2, l2);
        #pragma unroll
        for (int hh = 0; hh < 4; ++hh) {
            double s = (double)eb3[e * 4 + hh];
            #pragma unroll
            for (int i = 0; i < 4; ++i) s += l2[i] * (double)ew3[(e * 4 + i) * 4 + hh];
            h3[hh] = mishd(s);
        }
        double g = gv[e] * inv;
        #pragma unroll
        for (int hh = 0; hh < 4; ++hh) {
            double s = (double)eb4[e * 4 + hh];
            #pragma unroll
            for (int i = 0; i < 4; ++i) s += h3[i] * (double)ew4[(e * 4 + i) * 4 + hh];
            est[hh] += g * s;
        }
    }

    // logits + gumbel + first-max argmax
    const double ulo = (double)1e-10f, uhi = (double)(1.0f - 1e-7f);
    double best = -1e300; int kb = 0;
    #pragma unroll
    for (int n = 0; n < 4; ++n) {
        double lg = 0.0;
        #pragma unroll
        for (int l = 0; l < 4; ++l) lg += est[l] * (double)cb[n * 4 + l];
        double u = (double)gu[(size_t)row * 4 + n];
        u = fmin(fmax(u, ulo), uhi);
        double z = lg - log(-log(u));   // TAU = 1
        if (z > best) { best = z; kb = n; }
    }

    // decoder gate softmax + expert combine
    double g2[8], mx2 = -1e300, gs2 = 0.0;
    #pragma unroll
    for (int e = 0; e < 8; ++e) {
        g2[e] = (double)dgw[kb * 8 + e] + (double)dgb[e];
        mx2 = fmax(mx2, g2[e]);
    }
    #pragma unroll
    for (int e = 0; e < 8; ++e) { g2[e] = exp(g2[e] - mx2); gs2 += g2[e]; }
    double inv2 = 1.0 / gs2;

    float o[8];
    #pragma unroll
    for (int j = 0; j < 8; ++j) {
        double s = 0.0;
        #pragma unroll
        for (int e = 0; e < 8; ++e)
            s += g2[e] * (double)outE[((size_t)kb * 8 + e) * 8 + j];
        o[j] = (float)(s * inv2);
    }
    float* op = out + (size_t)row * 8;
    *reinterpret_cast<float4*>(op)     = make_float4(o[0], o[1], o[2], o[3]);
    *reinterpret_cast<float4*>(op + 4) = make_float4(o[4], o[5], o[6], o[7]);
}

// ---------------------------------------------------------------------------
extern "C" void kernel_launch(void* const* d_in, const int* in_sizes, int n_in,
                              void* d_out, int out_size, void* d_ws, size_t ws_size,
                              hipStream_t stream) {
    float* out = (float*)d_out;

    static const int expect[23] = {
        B_ROWS * DIN, B_ROWS * NE_, NE_ * 4,
        DIN * NEXP, NEXP,
        NEXP * DIN * 4, NEXP * 4,
        NEXP * 16, NEXP * 4,
        NEXP * 16, NEXP * 4,
        NEXP * 16, NEXP * 4,
        NE_ * NEXP, NEXP,
        NEXP * NE_ * HDEC, NEXP * HDEC,
        NEXP * HDEC * HDEC, NEXP * HDEC,
        NEXP * HDEC * HDEC, NEXP * HDEC,
        NEXP * HDEC * 8, NEXP * 8
    };
    // ws layout: w40t (1.31 MB f32) | outE (256 f32 + pad) | y (16384*40 f64)
    const size_t need = (size_t)(NCOL * DIN + 512) * sizeof(float)
                      + (size_t)B_ROWS * NCOL * sizeof(double);
    bool ok = (n_in == 23) && (out_size == B_ROWS * 8) && (ws_size >= need);
    if (ok) {
        for (int i = 0; i < 23; ++i) ok = ok && (in_sizes[i] == expect[i]);
    }
    if (!ok) {
        sentinel_k<<<(out_size + 255) / 256, 256, 0, stream>>>(out, out_size, 1.0e6f);
        return;
    }

    const float* x   = (const float*)d_in[0];
    const float* gu  = (const float*)d_in[1];
    const float* cb  = (const float*)d_in[2];
    const float* egw = (const float*)d_in[3];
    const float* egb = (const float*)d_in[4];
    const float* ew1 = (const float*)d_in[5];
    const float* eb1 = (const float*)d_in[6];
    const float* ew2 = (const float*)d_in[7];
    const float* eb2 = (const float*)d_in[8];
    const float* ew3 = (const float*)d_in[9];
    const float* eb3 = (const float*)d_in[10];
    const float* ew4 = (const float*)d_in[11];
    const float* eb4 = (const float*)d_in[12];
    const float* dgw = (const float*)d_in[13];
    const float* dgb = (const float*)d_in[14];
    const float* dw1 = (const float*)d_in[15];
    const float* db1 = (const float*)d_in[16];
    const float* dw2 = (const float*)d_in[17];
    const float* db2 = (const float*)d_in[18];
    const float* dw3 = (const float*)d_in[19];
    const float* db3 = (const float*)d_in[20];
    const float* dw4 = (const float*)d_in[21];
    const float* db4 = (const float*)d_in[22];

    float*  w40t = (float*)d_ws;                      // 40*8192 f32
    float*  outE = w40t + (size_t)NCOL * DIN;         // 256 f32 (+pad to 512)
    double* yws  = (double*)(w40t + (size_t)NCOL * DIN + 512);

    prep_all <<<PREP_BLOCKS + NE_ * NEXP, 256, 0, stream>>>(
        egw, ew1, w40t, dw1, db1, dw2, db2, dw3, db3, dw4, db4, outE);
    gemm_main<<<(B_ROWS / RPB) * 2, 256, 0, stream>>>(x, w40t, yws);
    tail_k   <<<B_ROWS / 64, 64, 0, stream>>>(yws, outE, gu, cb, egb, eb1,
                                              ew2, eb2, ew3, eb3, ew4, eb4,
                                              dgw, dgb, out);
}

// Round 18
// 386.508 us; speedup vs baseline: 1.2257x; 1.2257x over previous
//
#include <hip/hip_runtime.h>
#include <hip/hip_bf16.h>
#include <cstdint>

// Problem constants
#define B_ROWS 16384
#define DIN    8192
#define NE_    4      // codebook entries
#define NEXP   8
#define HDEC   256
#define NCOL   40     // 8 gate cols + 32 (e,lat) cols
#define CHUNK  256    // K per staged chunk (4 floats/lane)
#define NCHUNK (DIN / CHUNK)   // 32
#define RPB    8      // rows per block
#define CPW    5      // cols per wave
#define PREP_BLOCKS ((NCOL * DIN) / 256)   // 1280

typedef float f32x4 __attribute__((ext_vector_type(4)));

// ---------------- helpers ----------------
__device__ __forceinline__ float mishf(float x) {
    float sp = (x > 20.f) ? x : log1pf(expf(x));
    return x * tanhf(sp);
}
__device__ __forceinline__ double mishd(double x) {
    double sp = (x > 30.0) ? x : log1p(exp(x));
    return x * tanh(sp);
}
__device__ __forceinline__ void ln4d(const double* a, double* o) {
    double m  = (a[0] + a[1] + a[2] + a[3]) * 0.25;
    double d0 = a[0] - m, d1 = a[1] - m, d2 = a[2] - m, d3 = a[3] - m;
    double v  = (d0*d0 + d1*d1 + d2*d2 + d3*d3) * 0.25;
    double r  = 1.0 / sqrt(v + 1e-5);
    o[0] = d0*r; o[1] = d1*r; o[2] = d2*r; o[3] = d3*r;
}

// ---------------------------------------------------------------------------
__global__ __launch_bounds__(256) void sentinel_k(float* __restrict__ out, int n, float v) {
    int i = blockIdx.x * 256 + threadIdx.x;
    if (i < n) out[i] = v;
}

// ---------------------------------------------------------------------------
// Kernel 1 (merged): blocks [0,1280) pack w40T; blocks [1280,1312) compute
// decoder expert outputs outE[c][e][8] (one block per (c,e)). Both 256 thr.
// ---------------------------------------------------------------------------
__device__ __forceinline__ float blk_sum256(float v, volatile float* red) {
    #pragma unroll
    for (int off = 32; off > 0; off >>= 1) v += __shfl_down(v, off, 64);
    int lane = threadIdx.x & 63, w = threadIdx.x >> 6;
    if (lane == 0) red[w] = v;
    __syncthreads();
    float s = red[0] + red[1] + red[2] + red[3];
    __syncthreads();
    return s;
}

__global__ __launch_bounds__(256) void prep_all(
    const float* __restrict__ gw,  const float* __restrict__ ew1,
    float* __restrict__ w40t,
    const float* __restrict__ w1,  const float* __restrict__ b1,
    const float* __restrict__ w2,  const float* __restrict__ b2,
    const float* __restrict__ w3,  const float* __restrict__ b3,
    const float* __restrict__ w4,  const float* __restrict__ b4,
    float* __restrict__ outE)
{
    __shared__ float h[HDEC];
    __shared__ float red[4];

    if (blockIdx.x < PREP_BLOCKS) {
        int idx = blockIdx.x * 256 + threadIdx.x;   // 40*8192 threads
        int j = idx >> 13, k = idx & (DIN - 1);
        float v;
        if (j < 8) {
            v = gw[k * 8 + j];
        } else {
            int e = (j - 8) >> 2, hh = (j - 8) & 3;
            v = ew1[((size_t)e * DIN + k) * 4 + hh];
        }
        w40t[idx] = v;   // coalesced write
        return;
    }

    int bid = blockIdx.x - PREP_BLOCKS;
    int c = bid >> 3, e = bid & 7, t = threadIdx.x;

    float a   = mishf(w1[((size_t)e * NE_ + c) * HDEC + t] + b1[e * HDEC + t]);
    float m   = blk_sum256(a, red) * (1.f / HDEC);
    float d   = a - m;
    float var = blk_sum256(d * d, red) * (1.f / HDEC);
    h[t] = d * rsqrtf(var + 1e-5f);
    __syncthreads();

    float s = b2[e * HDEC + t];
    #pragma unroll 16
    for (int i = 0; i < HDEC; ++i) s += h[i] * w2[((size_t)e * HDEC + i) * HDEC + t];
    __syncthreads();
    a   = mishf(s);
    m   = blk_sum256(a, red) * (1.f / HDEC);
    d   = a - m;
    var = blk_sum256(d * d, red) * (1.f / HDEC);
    h[t] = d * rsqrtf(var + 1e-5f);
    __syncthreads();

    s = b3[e * HDEC + t];
    #pragma unroll 16
    for (int i = 0; i < HDEC; ++i) s += h[i] * w3[((size_t)e * HDEC + i) * HDEC + t];
    __syncthreads();
    float h3 = mishf(s);

    for (int j = 0; j < 8; ++j) {
        float oj = blk_sum256(h3 * w4[((size_t)e * HDEC + t) * 8 + j], red);
        if (t == 0) outE[((size_t)c * 8 + e) * 8 + j] = oj + b4[e * 8 + j];
    }
}

// ---------------------------------------------------------------------------
// Kernel 2: skinny GEMM, small barrier domains + XCD-twin swizzle.
// 4096 blocks x 256 threads (4 waves). Block = (rowGroup, colHalf) with
//   rowGroup = (bid>>4)*8 + (bid&7),  colHalf = (bid>>3)&1
// so the two col-halves of a row-group differ by 8 in blockIdx -> same XCD
// under round-robin and adjacent dispatch -> the twin's x reads hit that
// XCD's L2 (x HBM traffic ~1x instead of 2x).
// Per-wave work, registers, FMA order, LDS pattern bit-identical to R12/R15
// (verified numerics). VGPR 56 -- below the 64-VGPR occupancy cliff, which
// 6 rounds of experiments showed is the binding constraint on this compiler.
// ---------------------------------------------------------------------------
__global__ __launch_bounds__(256) void gemm_main(
    const float* __restrict__ x, const float* __restrict__ w40t,
    double* __restrict__ y)
{
    __shared__ float xbuf[2][RPB][CHUNK];   // 16384 B

    const int t    = threadIdx.x;
    const int lane = t & 63;
    const int wv   = t >> 6;            // 0..3
    const int bid  = blockIdx.x;
    const int rowGroup = (bid >> 4) * 8 + (bid & 7);   // 0..2047 (bijective)
    const int colHalf  = (bid >> 3) & 1;
    const int rowBase  = rowGroup * RPB;
    const int j0   = colHalf * 20 + wv * CPW;

    typedef const char __attribute__((address_space(1)))* gp_t;
    typedef char __attribute__((address_space(3)))* lp_t;

    const float* __restrict__ xsrcA = x + (size_t)(rowBase + wv)     * DIN + (lane << 2);
    const float* __restrict__ xsrcB = x + (size_t)(rowBase + wv + 4) * DIN + (lane << 2);
    const float* __restrict__ wr    = w40t + (size_t)j0 * DIN + (lane << 2);

    float acc[RPB][CPW];
    #pragma unroll
    for (int r = 0; r < RPB; ++r)
        #pragma unroll
        for (int jj = 0; jj < CPW; ++jj) acc[r][jj] = 0.f;

    // ---- prologue: stage chunk 0 into buf 0 (wave wv: rows wv, wv+4)
    __builtin_amdgcn_global_load_lds(
        (gp_t)(const void*)xsrcA,
        (lp_t)(void*)(&xbuf[0][wv][lane << 2]), 16, 0, 0);
    __builtin_amdgcn_global_load_lds(
        (gp_t)(const void*)xsrcB,
        (lp_t)(void*)(&xbuf[0][wv + 4][lane << 2]), 16, 0, 0);
    __syncthreads();   // drain: chunk-0 stage complete

    for (int c = 0; c < NCHUNK; ++c) {
        const int cur = c & 1;

        // 1) w loads FIRST (oldest in vmcnt queue -> FMAs wait only on them)
        f32x4 wv0 = *(const f32x4*)(wr + (size_t)c * CHUNK);
        f32x4 wv1 = *(const f32x4*)(wr + (size_t)DIN     + (size_t)c * CHUNK);
        f32x4 wv2 = *(const f32x4*)(wr + 2 * (size_t)DIN + (size_t)c * CHUNK);
        f32x4 wv3 = *(const f32x4*)(wr + 3 * (size_t)DIN + (size_t)c * CHUNK);
        f32x4 wv4 = *(const f32x4*)(wr + 4 * (size_t)DIN + (size_t)c * CHUNK);
        __builtin_amdgcn_sched_barrier(0);

        // 2) async stage of chunk c+1 (youngest; in flight across FMA phase)
        if (c + 1 < NCHUNK) {
            __builtin_amdgcn_global_load_lds(
                (gp_t)(const void*)(xsrcA + (size_t)(c + 1) * CHUNK),
                (lp_t)(void*)(&xbuf[cur ^ 1][wv][lane << 2]), 16, 0, 0);
            __builtin_amdgcn_global_load_lds(
                (gp_t)(const void*)(xsrcB + (size_t)(c + 1) * CHUNK),
                (lp_t)(void*)(&xbuf[cur ^ 1][wv + 4][lane << 2]), 16, 0, 0);
        }
        __builtin_amdgcn_sched_barrier(0);

        // 3) rows from LDS (ds_read_b128), FMA order == R12 (verified)
        #pragma unroll
        for (int r = 0; r < RPB; ++r) {
            f32x4 xv = *(const f32x4*)(&xbuf[cur][r][lane << 2]);
            float a0 = acc[r][0];
            a0 = fmaf(xv.x, wv0.x, a0); a0 = fmaf(xv.y, wv0.y, a0);
            a0 = fmaf(xv.z, wv0.z, a0); a0 = fmaf(xv.w, wv0.w, a0);
            acc[r][0] = a0;
            float a1 = acc[r][1];
            a1 = fmaf(xv.x, wv1.x, a1); a1 = fmaf(xv.y, wv1.y, a1);
            a1 = fmaf(xv.z, wv1.z, a1); a1 = fmaf(xv.w, wv1.w, a1);
            acc[r][1] = a1;
            float a2 = acc[r][2];
            a2 = fmaf(xv.x, wv2.x, a2); a2 = fmaf(xv.y, wv2.y, a2);
            a2 = fmaf(xv.z, wv2.z, a2); a2 = fmaf(xv.w, wv2.w, a2);
            acc[r][2] = a2;
            float a3 = acc[r][3];
            a3 = fmaf(xv.x, wv3.x, a3); a3 = fmaf(xv.y, wv3.y, a3);
            a3 = fmaf(xv.z, wv3.z, a3); a3 = fmaf(xv.w, wv3.w, a3);
            acc[r][3] = a3;
            float a4 = acc[r][4];
            a4 = fmaf(xv.x, wv4.x, a4); a4 = fmaf(xv.y, wv4.y, a4);
            a4 = fmaf(xv.z, wv4.z, a4); a4 = fmaf(xv.w, wv4.w, a4);
            acc[r][4] = a4;
        }

        __syncthreads();   // drains next-chunk stage (covered by FMA phase)
    }

    // ---- f64 cross-lane reduction (identical to R6/R12, verified)
    #pragma unroll
    for (int r = 0; r < RPB; ++r) {
        #pragma unroll
        for (int jj = 0; jj < CPW; ++jj) {
            double v = (double)acc[r][jj];
            #pragma unroll
            for (int off = 32; off > 0; off >>= 1) v += __shfl_xor(v, off, 64);
            if (lane == 0) y[(size_t)(rowBase + r) * NCOL + (j0 + jj)] = v;
        }
    }
}

// ---------------------------------------------------------------------------
// Kernel 3: per-row f64 tail (verified math). 1 thread = 1 row.
// 256 blocks x 64 threads -> one wave per CU across all 256 CUs.
// ---------------------------------------------------------------------------
__global__ __launch_bounds__(64) void tail_k(
    const double* __restrict__ yg, const float* __restrict__ outE,
    const float* __restrict__ gu,  const float* __restrict__ cb,
    const float* __restrict__ egb, const float* __restrict__ eb1,
    const float* __restrict__ ew2, const float* __restrict__ eb2,
    const float* __restrict__ ew3, const float* __restrict__ eb3,
    const float* __restrict__ ew4, const float* __restrict__ eb4,
    const float* __restrict__ dgw, const float* __restrict__ dgb,
    float* __restrict__ out)
{
    const int row = blockIdx.x * 64 + threadIdx.x;
    const double* __restrict__ y = yg + (size_t)row * NCOL;

    // encoder gate softmax
    double gv[8], mx = -1e300, gs = 0.0;
    #pragma unroll
    for (int e = 0; e < 8; ++e) { gv[e] = y[e] + (double)egb[e]; mx = fmax(mx, gv[e]); }
    #pragma unroll
    for (int e = 0; e < 8; ++e) { gv[e] = exp(gv[e] - mx); gs += gv[e]; }
    double inv = 1.0 / gs;

    double est[4] = {0, 0, 0, 0};
    #pragma unroll
    for (int e = 0; e < 8; ++e) {
        double a[4], l1[4], p2[4], l2[4], h3[4];
        #pragma unroll
        for (int hh = 0; hh < 4; ++hh)
            a[hh] = mishd(y[8 + e * 4 + hh] + (double)eb1[e * 4 + hh]);
        ln4d(a, l1);
        #pragma unroll
        for (int hh = 0; hh < 4; ++hh) {
            double s = (double)eb2[e * 4 + hh];
            #pragma unroll
            for (int i = 0; i < 4; ++i) s += l1[i] * (double)ew2[(e * 4 + i) * 4 + hh];
            p2[hh] = mishd(s);
        }
        ln4d(p2, l2);
        #pragma unroll
        for (int hh = 0; hh < 4; ++hh) {
            double s = (double)eb3[e * 4 + hh];
            #pragma unroll
            for (int i = 0; i < 4; ++i) s += l2[i] * (double)ew3[(e * 4 + i) * 4 + hh];
            h3[hh] = mishd(s);
        }
        double g = gv[e] * inv;
        #pragma unroll
        for (int hh = 0; hh < 4; ++hh) {
            double s = (double)eb4[e * 4 + hh];
            #pragma unroll
            for (int i = 0; i < 4; ++i) s += h3[i] * (double)ew4[(e * 4 + i) * 4 + hh];
            est[hh] += g * s;
        }
    }

    // logits + gumbel + first-max argmax
    const double ulo = (double)1e-10f, uhi = (double)(1.0f - 1e-7f);
    double best = -1e300; int kb = 0;
    #pragma unroll
    for (int n = 0; n < 4; ++n) {
        double lg = 0.0;
        #pragma unroll
        for (int l = 0; l < 4; ++l) lg += est[l] * (double)cb[n * 4 + l];
        double u = (double)gu[(size_t)row * 4 + n];
        u = fmin(fmax(u, ulo), uhi);
        double z = lg - log(-log(u));   // TAU = 1
        if (z > best) { best = z; kb = n; }
    }

    // decoder gate softmax + expert combine
    double g2[8], mx2 = -1e300, gs2 = 0.0;
    #pragma unroll
    for (int e = 0; e < 8; ++e) {
        g2[e] = (double)dgw[kb * 8 + e] + (double)dgb[e];
        mx2 = fmax(mx2, g2[e]);
    }
    #pragma unroll
    for (int e = 0; e < 8; ++e) { g2[e] = exp(g2[e] - mx2); gs2 += g2[e]; }
    double inv2 = 1.0 / gs2;

    float o[8];
    #pragma unroll
    for (int j = 0; j < 8; ++j) {
        double s = 0.0;
        #pragma unroll
        for (int e = 0; e < 8; ++e)
            s += g2[e] * (double)outE[((size_t)kb * 8 + e) * 8 + j];
        o[j] = (float)(s * inv2);
    }
    float* op = out + (size_t)row * 8;
    *reinterpret_cast<float4*>(op)     = make_float4(o[0], o[1], o[2], o[3]);
    *reinterpret_cast<float4*>(op + 4) = make_float4(o[4], o[5], o[6], o[7]);
}

// ---------------------------------------------------------------------------
extern "C" void kernel_launch(void* const* d_in, const int* in_sizes, int n_in,
                              void* d_out, int out_size, void* d_ws, size_t ws_size,
                              hipStream_t stream) {
    float* out = (float*)d_out;

    static const int expect[23] = {
        B_ROWS * DIN, B_ROWS * NE_, NE_ * 4,
        DIN * NEXP, NEXP,
        NEXP * DIN * 4, NEXP * 4,
        NEXP * 16, NEXP * 4,
        NEXP * 16, NEXP * 4,
        NEXP * 16, NEXP * 4,
        NE_ * NEXP, NEXP,
        NEXP * NE_ * HDEC, NEXP * HDEC,
        NEXP * HDEC * HDEC, NEXP * HDEC,
        NEXP * HDEC * HDEC, NEXP * HDEC,
        NEXP * HDEC * 8, NEXP * 8
    };
    // ws layout: w40t (1.31 MB f32) | outE (256 f32 + pad) | y (16384*40 f64)
    const size_t need = (size_t)(NCOL * DIN + 512) * sizeof(float)
                      + (size_t)B_ROWS * NCOL * sizeof(double);
    bool ok = (n_in == 23) && (out_size == B_ROWS * 8) && (ws_size >= need);
    if (ok) {
        for (int i = 0; i < 23; ++i) ok = ok && (in_sizes[i] == expect[i]);
    }
    if (!ok) {
        sentinel_k<<<(out_size + 255) / 256, 256, 0, stream>>>(out, out_size, 1.0e6f);
        return;
    }

    const float* x   = (const float*)d_in[0];
    const float* gu  = (const float*)d_in[1];
    const float* cb  = (const float*)d_in[2];
    const float* egw = (const float*)d_in[3];
    const float* egb = (const float*)d_in[4];
    const float* ew1 = (const float*)d_in[5];
    const float* eb1 = (const float*)d_in[6];
    const float* ew2 = (const float*)d_in[7];
    const float* eb2 = (const float*)d_in[8];
    const float* ew3 = (const float*)d_in[9];
    const float* eb3 = (const float*)d_in[10];
    const float* ew4 = (const float*)d_in[11];
    const float* eb4 = (const float*)d_in[12];
    const float* dgw = (const float*)d_in[13];
    const float* dgb = (const float*)d_in[14];
    const float* dw1 = (const float*)d_in[15];
    const float* db1 = (const float*)d_in[16];
    const float* dw2 = (const float*)d_in[17];
    const float* db2 = (const float*)d_in[18];
    const float* dw3 = (const float*)d_in[19];
    const float* db3 = (const float*)d_in[20];
    const float* dw4 = (const float*)d_in[21];
    const float* db4 = (const float*)d_in[22];

    float*  w40t = (float*)d_ws;                      // 40*8192 f32
    float*  outE = w40t + (size_t)NCOL * DIN;         // 256 f32 (+pad to 512)
    double* yws  = (double*)(w40t + (size_t)NCOL * DIN + 512);

    prep_all <<<PREP_BLOCKS + NE_ * NEXP, 256, 0, stream>>>(
        egw, ew1, w40t, dw1, db1, dw2, db2, dw3, db3, dw4, db4, outE);
    gemm_main<<<(B_ROWS / RPB) * 2, 256, 0, stream>>>(x, w40t, yws);
    tail_k   <<<B_ROWS / 64, 64, 0, stream>>>(yws, outE, gu, cb, egb, eb1,
                                              ew2, eb2, ew3, eb3, ew4, eb4,
                                              dgw, dgb, out);
}